// Round 10
// baseline (342.880 us; speedup 1.0000x reference)
//
#include <hip/hip_runtime.h>
#include <hip/hip_bf16.h>
#include <math.h>

#define BB 16
#define CC 3
#define HH 512
#define WW 1024
#define NN (HH * WW)          // 524288 = 2^19
#define BN ((size_t)BB * NN)  // 8388608 = 2^23

typedef __attribute__((ext_vector_type(4))) _Float16 half4;
typedef __attribute__((ext_vector_type(2))) _Float16 h2;
typedef __attribute__((ext_vector_type(4))) float f4;

// ws layout (bytes), first 8 KB zeroed each launch:
//   0    : double sum_part[64]     (0..511)
//   512  : double acc_ls[64]       (512..1023)
//   1024 : double acc_ss[64]       (1024..1535)
//   1536 : uint   cnt_nz[64]       (1536..1791)
//   1792 : uint   cnt_zz[64]       (1792..2047)
//   2048 : int    nval[16]         (2048..2111)
//   3584 : uint   done             (no overlap with anything)
//   4096 : int    counts[1024]     (raw per-8192px-chunk valid counts)
//   8192 : uint   mask[BN/32]      invalid bits, 1 MB
//   2MB  : h2     val_list[BN]     (gt_val, pred_val) compacted, 33.5 MB
//          region doubles as tw[BN] (_Float16, 16.8 MB) before scatter.

// 8 rows per block (1024 blocks), register-carried vertical neighbor:
// reads 9 rows, computes 8 -> img traffic 1.125x.
__global__ __launch_bounds__(256) void tw_sum_kernel(const float* __restrict__ img,
                                                     double* __restrict__ sum_part,
                                                     _Float16* __restrict__ tw_out) {
    int t = threadIdx.x;
    int bid = blockIdx.x;                  // 1024 = 16 imgs * 64 row-groups
    int b = bid >> 6;
    int h0 = (bid & 63) * 8;
    const float* base = img + (size_t)b * CC * NN;
    int w0 = t * 4;
    bool haveR = (w0 < WW - 4);
    size_t rb = (size_t)h0 * WW + w0;
    f4 c0 = *(const f4*)(base + rb);
    f4 c1 = *(const f4*)(base + NN + rb);
    f4 c2 = *(const f4*)(base + 2 * NN + rb);
    float e0 = haveR ? base[rb + 4] : 0.f;
    float e1 = haveR ? base[NN + rb + 4] : 0.f;
    float e2 = haveR ? base[2 * NN + rb + 4] : 0.f;
    float rowacc = 0.f;
    #pragma unroll
    for (int r = 0; r < 8; ++r) {
        int h = h0 + r;
        bool haveD = (h < HH - 1);
        size_t db = (size_t)(h + 1) * WW + w0;
        f4 d0, d1, d2;
        float f0, f1, f2;
        if (haveD) {
            d0 = *(const f4*)(base + db);
            d1 = *(const f4*)(base + NN + db);
            d2 = *(const f4*)(base + 2 * NN + db);
            f0 = haveR ? base[db + 4] : 0.f;
            f1 = haveR ? base[NN + db + 4] : 0.f;
            f2 = haveR ? base[2 * NN + db + 4] : 0.f;
        } else {
            d0 = d1 = d2 = (f4)0.f;
            f0 = f1 = f2 = 0.f;
        }
        float a0[5] = {c0.x, c0.y, c0.z, c0.w, e0};
        float a1[5] = {c1.x, c1.y, c1.z, c1.w, e1};
        float a2[5] = {c2.x, c2.y, c2.z, c2.w, e2};
        float b0[4] = {d0.x, d0.y, d0.z, d0.w};
        float b1[4] = {d1.x, d1.y, d1.z, d1.w};
        float b2[4] = {d2.x, d2.y, d2.z, d2.w};
        float tw[4];
        #pragma unroll
        for (int j = 0; j < 4; ++j) {
            float twv = 0.f;
            if (w0 + j < WW - 1)
                twv += (fabsf(a0[j]-a0[j+1]) + fabsf(a1[j]-a1[j+1]) + fabsf(a2[j]-a2[j+1])) / 3.0f;
            if (haveD)
                twv += (fabsf(a0[j]-b0[j]) + fabsf(a1[j]-b1[j]) + fabsf(a2[j]-b2[j])) / 3.0f;
            tw[j] = twv * 0.5f;
        }
        half4 hv; hv.x = (_Float16)tw[0]; hv.y = (_Float16)tw[1];
        hv.z = (_Float16)tw[2]; hv.w = (_Float16)tw[3];
        *(half4*)(tw_out + (size_t)b * NN + (size_t)h * WW + w0) = hv;
        rowacc += (tw[0] + tw[1]) + (tw[2] + tw[3]);
        c0 = d0; c1 = d1; c2 = d2; e0 = f0; e1 = f1; e2 = f2;
    }
    double acc = (double)rowacc;
    int lane = t & 63, wid = t >> 6;
    for (int o = 32; o > 0; o >>= 1) acc += __shfl_down(acc, o);
    __shared__ double sd[4];
    if (lane == 0) sd[wid] = acc;
    __syncthreads();
    if (t == 0) atomicAdd(&sum_part[bid & 63], sd[0]+sd[1]+sd[2]+sd[3]);
}

// 8192 blocks x 256 t x 4 px; writes mask bits, raw chunk counts, nval.
__global__ __launch_bounds__(256) void mask_kernel(const _Float16* __restrict__ tw_in,
                                                   const double* __restrict__ sum_part,
                                                   unsigned int* __restrict__ mask,
                                                   int* __restrict__ counts,
                                                   int* __restrict__ nval) {
    __shared__ float s_mean;
    __shared__ unsigned int wds[32];
    __shared__ int sv[4];
    int t = threadIdx.x;
    if (t == 0) {
        double s = 0.0;
        for (int i = 0; i < 64; ++i) s += sum_part[i];
        s_mean = (float)(s / (double)BN);
    }
    if (t < 32) wds[t] = 0;
    __syncthreads();
    float mean = s_mean;
    size_t g0 = ((size_t)blockIdx.x * 256 + t) * 4;
    half4 hv = *(const half4*)(tw_in + g0);
    unsigned int nib = ((float)hv.x < mean ? 1u : 0u) | ((float)hv.y < mean ? 2u : 0u)
                     | ((float)hv.z < mean ? 4u : 0u) | ((float)hv.w < mean ? 8u : 0u);
    atomicOr(&wds[t >> 3], nib << ((t & 7) * 4));
    int cv = 4 - __popc(nib);
    int lane = t & 63, wid = t >> 6;
    for (int o = 32; o > 0; o >>= 1) cv += __shfl_down(cv, o);
    if (lane == 0) sv[wid] = cv;
    __syncthreads();
    if (t < 32) mask[(size_t)blockIdx.x * 32 + t] = wds[t];
    if (t == 0) {
        int tot = sv[0] + sv[1] + sv[2] + sv[3];
        atomicAdd(&counts[blockIdx.x >> 3], tot);
        atomicAdd(&nval[blockIdx.x >> 9], tot);
    }
}

// Compaction: val[rank] = (gt, pred) at each valid pos; row prefix computed in-block.
__global__ __launch_bounds__(256) void scatter_kernel(const unsigned int* __restrict__ mask,
                                                      const int* __restrict__ counts,
                                                      const float* __restrict__ gt,
                                                      const float* __restrict__ pred,
                                                      h2* __restrict__ val) {
    int cglob = blockIdx.x;        // 0..1023 (chunk of 8192 px)
    int b  = cglob >> 6;
    int cl = cglob & 63;
    int t = threadIdx.x;
    __shared__ unsigned int svb[256];
    __shared__ int swoff[256];
    __shared__ int wsum[4];
    __shared__ int schunkbase;
    if (t < 64) {                  // wave 0: exclusive prefix of this row's 64 chunk counts
        int v = counts[b * 64 + t];
        int incl = v;
        for (int o = 1; o < 64; o <<= 1) {
            int n = __shfl_up(incl, o);
            if (t >= o) incl += n;
        }
        if (t == cl) schunkbase = incl - v;
    }
    unsigned int vb = ~mask[(size_t)cglob * 256 + t];
    svb[t] = vb;
    int cnt = __popc(vb);
    int lane = t & 63, wid = t >> 6;
    int incl = cnt;
    for (int o = 1; o < 64; o <<= 1) {
        int n = __shfl_up(incl, o);
        if (lane >= o) incl += n;
    }
    if (lane == 63) wsum[wid] = incl;
    __syncthreads();
    int woff = 0;
    for (int i = 0; i < wid; i++) woff += wsum[i];
    swoff[t] = woff + incl - cnt;
    __syncthreads();
    size_t rowb = (size_t)b << 19;
    int chunkbase = schunkbase;
    size_t gbase = rowb + (size_t)cl * 8192;
    int bit = t & 31;
    unsigned int below = (bit == 0) ? 0u : ((1u << bit) - 1u);
    #pragma unroll 4
    for (int i = 0; i < 32; ++i) {
        int e = i * 256 + t;
        unsigned int bits = svb[i * 8 + (t >> 5)];
        if ((bits >> bit) & 1u) {
            int rank = chunkbase + swoff[i * 8 + (t >> 5)] + __popc(bits & below);
            size_t src = gbase + e;
            h2 o; o.x = (_Float16)gt[src]; o.y = (_Float16)pred[src];
            val[rowb + rank] = o;
        }
    }
}

__device__ __forceinline__ float fget(const f4& v, int k) {
    switch (k) { case 0: return v.x; case 1: return v.y; case 2: return v.z; default: return v.w; }
}

// 8 px/thread, 4096 blocks; rows {2x,2x+1} -> XCD x; finalize folded via done-ctr.
__global__ __launch_bounds__(256) void loss_kernel(const float* __restrict__ pred,
                                                   const float* __restrict__ gt,
                                                   const float* __restrict__ ur,
                                                   const unsigned int* __restrict__ mask,
                                                   const h2* __restrict__ val,
                                                   const int* __restrict__ nv_arr,
                                                   double* __restrict__ acc_ls,
                                                   double* __restrict__ acc_ss,
                                                   unsigned int* __restrict__ cnt_nz,
                                                   unsigned int* __restrict__ cnt_zz,
                                                   unsigned int* __restrict__ done,
                                                   float* __restrict__ out) {
    int t = threadIdx.x;
    int bid = blockIdx.x;                       // 4096 blocks
    int b = ((bid & 7) << 1) | ((bid >> 3) & 1);
    int chunk = bid >> 4;                       // 256 chunks per row
    size_t rowb = (size_t)b << 19;
    int n0 = (chunk << 11) + t * 8;
    size_t g0 = rowb + (size_t)n0;
    unsigned int bits =
        (__builtin_nontemporal_load(&mask[g0 >> 5]) >> ((t & 3) << 3)) & 0xFFu;
    int nv = nv_arr[b];
    float fnv = (float)nv;
    f4 U[2], G[2], P[2];
    const f4* up = (const f4*)(ur + g0);
    const f4* gp = (const f4*)(gt + g0);
    const f4* pp = (const f4*)(pred + g0);
    #pragma unroll
    for (int i = 0; i < 2; ++i) {
        U[i] = __builtin_nontemporal_load(up + i);
        G[i] = __builtin_nontemporal_load(gp + i);
        P[i] = __builtin_nontemporal_load(pp + i);
    }
    float ls = 0.f, ss = 0.f;
    int cnz = 0, czz = 0;
    #pragma unroll
    for (int j = 0; j < 8; ++j) {
        if ((bits >> j) & 1u) {                 // invalid pixel
            float urv = fget(U[j >> 2], j & 3);
            int u = min((int)(urv * fnv), nv - 1);
            h2 v = val[rowb + (size_t)u];
            float vx = (float)v.x, vy = (float)v.y;
            float gc = fget(G[j >> 2], j & 3);
            float pc = fget(P[j >> 2], j & 3);
            float d = pc - vy;
            if (gc >= 1.02f * vx)      { ls += __logf(1.f + __expf(-d)); ++cnz; }
            else if (vx > 1.02f * gc)  { ls += __logf(1.f + __expf( d)); ++cnz; }
            else                       { ss += d * d; ++czz; }
        }
    }
    int lane = t & 63, wid = t >> 6;
    __shared__ double sd[4];
    __shared__ unsigned int si[4];
    double lsd = (double)ls, ssd = (double)ss;
    for (int o = 32; o > 0; o >>= 1) lsd += __shfl_down(lsd, o);
    if (lane == 0) sd[wid] = lsd;
    __syncthreads();
    if (t == 0) atomicAdd(&acc_ls[bid & 63], sd[0]+sd[1]+sd[2]+sd[3]);
    __syncthreads();
    for (int o = 32; o > 0; o >>= 1) ssd += __shfl_down(ssd, o);
    if (lane == 0) sd[wid] = ssd;
    __syncthreads();
    if (t == 0) atomicAdd(&acc_ss[bid & 63], sd[0]+sd[1]+sd[2]+sd[3]);
    __syncthreads();
    for (int o = 32; o > 0; o >>= 1) cnz += __shfl_down(cnz, o);
    if (lane == 0) si[wid] = (unsigned int)cnz;
    __syncthreads();
    if (t == 0) atomicAdd(&cnt_nz[bid & 63], si[0]+si[1]+si[2]+si[3]);
    __syncthreads();
    for (int o = 32; o > 0; o >>= 1) czz += __shfl_down(czz, o);
    if (lane == 0) si[wid] = (unsigned int)czz;
    __syncthreads();
    if (t == 0) {
        atomicAdd(&cnt_zz[bid & 63], si[0]+si[1]+si[2]+si[3]);
        __threadfence();
        unsigned int prev = atomicAdd(done, 1u);
        if (prev == (unsigned int)(gridDim.x - 1)) {   // last block finalizes
            double l = 0.0, s2 = 0.0;
            unsigned long long a = 0, c = 0;
            for (int i = 0; i < 64; ++i) {
                l  += __hip_atomic_load(&acc_ls[i], __ATOMIC_RELAXED, __HIP_MEMORY_SCOPE_AGENT);
                s2 += __hip_atomic_load(&acc_ss[i], __ATOMIC_RELAXED, __HIP_MEMORY_SCOPE_AGENT);
                a  += __hip_atomic_load(&cnt_nz[i], __ATOMIC_RELAXED, __HIP_MEMORY_SCOPE_AGENT);
                c  += __hip_atomic_load(&cnt_zz[i], __ATOMIC_RELAXED, __HIP_MEMORY_SCOPE_AGENT);
            }
            out[0] = (float)(l / (double)a + s2 / (double)c);
        }
    }
}

extern "C" void kernel_launch(void* const* d_in, const int* in_sizes, int n_in,
                              void* d_out, int out_size, void* d_ws, size_t ws_size,
                              hipStream_t stream) {
    const float* pred = (const float*)d_in[0];
    const float* gt   = (const float*)d_in[1];
    const float* img  = (const float*)d_in[2];
    const float* ur   = (const float*)d_in[3];
    float* out = (float*)d_out;

    char* ws = (char*)d_ws;
    double*       sum_part = (double*)(ws + 0);
    double*       acc_ls   = (double*)(ws + 512);
    double*       acc_ss   = (double*)(ws + 1024);
    unsigned int* cnt_nz   = (unsigned int*)(ws + 1536);
    unsigned int* cnt_zz   = (unsigned int*)(ws + 1792);
    int*          nval     = (int*)(ws + 2048);
    unsigned int* done     = (unsigned int*)(ws + 3584);
    int*          counts   = (int*)(ws + 4096);
    unsigned int* mask     = (unsigned int*)(ws + 8192);
    h2*           val      = (h2*)(ws + (1 << 21));
    _Float16*     tw       = (_Float16*)(ws + (1 << 21));   // aliases val (pre-scatter)

    (void)hipMemsetAsync(ws, 0, 8192, stream);
    tw_sum_kernel <<<1024, 256, 0, stream>>>(img, sum_part, tw);
    mask_kernel   <<<8192, 256, 0, stream>>>(tw, sum_part, mask, counts, nval);
    scatter_kernel<<<1024, 256, 0, stream>>>(mask, counts, gt, pred, val);
    loss_kernel   <<<4096, 256, 0, stream>>>(pred, gt, ur, mask, val, nval,
                                             acc_ls, acc_ss, cnt_nz, cnt_zz, done, out);
}

// Round 11
// 193.104 us; speedup vs baseline: 1.7756x; 1.7756x over previous
//
#include <hip/hip_runtime.h>
#include <hip/hip_bf16.h>
#include <math.h>

#define BB 16
#define CC 3
#define HH 512
#define WW 1024
#define NN (HH * WW)          // 524288 = 2^19
#define BN ((size_t)BB * NN)  // 8388608 = 2^23

typedef __attribute__((ext_vector_type(4))) _Float16 half4;
typedef __attribute__((ext_vector_type(2))) _Float16 h2;
typedef __attribute__((ext_vector_type(4))) float f4;

// ws layout (bytes), first 8 KB zeroed each launch:
//   0    : double sum_part[64]     (0..511)
//   512  : double acc_ls[64]       (512..1023)
//   1024 : double acc_ss[64]       (1024..1535)
//   1536 : uint   cnt_nz[64]       (1536..1791)
//   1792 : uint   cnt_zz[64]       (1792..2047)
//   2048 : int    nval[16]         (2048..2111)
//   4096 : int    counts[1024]     (raw per-8192px-chunk valid counts)
//   8192 : uint   mask[BN/32]      invalid bits, 1 MB
//   2MB  : h2     val_list[BN]     (gt_val, pred_val) compacted, 33.5 MB
//          region doubles as tw[BN] (_Float16, 16.8 MB) before scatter.

// 8 rows per block (1024 blocks), register-carried vertical neighbor:
// reads 9 rows, computes 8 -> img traffic 1.125x.
__global__ __launch_bounds__(256) void tw_sum_kernel(const float* __restrict__ img,
                                                     double* __restrict__ sum_part,
                                                     _Float16* __restrict__ tw_out) {
    int t = threadIdx.x;
    int bid = blockIdx.x;                  // 1024 = 16 imgs * 64 row-groups
    int b = bid >> 6;
    int h0 = (bid & 63) * 8;
    const float* base = img + (size_t)b * CC * NN;
    int w0 = t * 4;
    bool haveR = (w0 < WW - 4);
    size_t rb = (size_t)h0 * WW + w0;
    f4 c0 = *(const f4*)(base + rb);
    f4 c1 = *(const f4*)(base + NN + rb);
    f4 c2 = *(const f4*)(base + 2 * NN + rb);
    float e0 = haveR ? base[rb + 4] : 0.f;
    float e1 = haveR ? base[NN + rb + 4] : 0.f;
    float e2 = haveR ? base[2 * NN + rb + 4] : 0.f;
    float rowacc = 0.f;
    #pragma unroll
    for (int r = 0; r < 8; ++r) {
        int h = h0 + r;
        bool haveD = (h < HH - 1);
        size_t db = (size_t)(h + 1) * WW + w0;
        f4 d0, d1, d2;
        float f0, f1, f2;
        if (haveD) {
            d0 = *(const f4*)(base + db);
            d1 = *(const f4*)(base + NN + db);
            d2 = *(const f4*)(base + 2 * NN + db);
            f0 = haveR ? base[db + 4] : 0.f;
            f1 = haveR ? base[NN + db + 4] : 0.f;
            f2 = haveR ? base[2 * NN + db + 4] : 0.f;
        } else {
            d0 = d1 = d2 = (f4)0.f;
            f0 = f1 = f2 = 0.f;
        }
        float a0[5] = {c0.x, c0.y, c0.z, c0.w, e0};
        float a1[5] = {c1.x, c1.y, c1.z, c1.w, e1};
        float a2[5] = {c2.x, c2.y, c2.z, c2.w, e2};
        float b0[4] = {d0.x, d0.y, d0.z, d0.w};
        float b1[4] = {d1.x, d1.y, d1.z, d1.w};
        float b2[4] = {d2.x, d2.y, d2.z, d2.w};
        float tw[4];
        #pragma unroll
        for (int j = 0; j < 4; ++j) {
            float twv = 0.f;
            if (w0 + j < WW - 1)
                twv += (fabsf(a0[j]-a0[j+1]) + fabsf(a1[j]-a1[j+1]) + fabsf(a2[j]-a2[j+1])) / 3.0f;
            if (haveD)
                twv += (fabsf(a0[j]-b0[j]) + fabsf(a1[j]-b1[j]) + fabsf(a2[j]-b2[j])) / 3.0f;
            tw[j] = twv * 0.5f;
        }
        half4 hv; hv.x = (_Float16)tw[0]; hv.y = (_Float16)tw[1];
        hv.z = (_Float16)tw[2]; hv.w = (_Float16)tw[3];
        *(half4*)(tw_out + (size_t)b * NN + (size_t)h * WW + w0) = hv;
        rowacc += (tw[0] + tw[1]) + (tw[2] + tw[3]);
        c0 = d0; c1 = d1; c2 = d2; e0 = f0; e1 = f1; e2 = f2;
    }
    double acc = (double)rowacc;
    int lane = t & 63, wid = t >> 6;
    for (int o = 32; o > 0; o >>= 1) acc += __shfl_down(acc, o);
    __shared__ double sd[4];
    if (lane == 0) sd[wid] = acc;
    __syncthreads();
    if (t == 0) atomicAdd(&sum_part[bid & 63], sd[0]+sd[1]+sd[2]+sd[3]);
}

// 8192 blocks x 256 t x 4 px; writes mask bits, raw chunk counts, nval.
__global__ __launch_bounds__(256) void mask_kernel(const _Float16* __restrict__ tw_in,
                                                   const double* __restrict__ sum_part,
                                                   unsigned int* __restrict__ mask,
                                                   int* __restrict__ counts,
                                                   int* __restrict__ nval) {
    __shared__ float s_mean;
    __shared__ unsigned int wds[32];
    __shared__ int sv[4];
    int t = threadIdx.x;
    if (t == 0) {
        double s = 0.0;
        for (int i = 0; i < 64; ++i) s += sum_part[i];
        s_mean = (float)(s / (double)BN);
    }
    if (t < 32) wds[t] = 0;
    __syncthreads();
    float mean = s_mean;
    size_t g0 = ((size_t)blockIdx.x * 256 + t) * 4;
    half4 hv = *(const half4*)(tw_in + g0);
    unsigned int nib = ((float)hv.x < mean ? 1u : 0u) | ((float)hv.y < mean ? 2u : 0u)
                     | ((float)hv.z < mean ? 4u : 0u) | ((float)hv.w < mean ? 8u : 0u);
    atomicOr(&wds[t >> 3], nib << ((t & 7) * 4));
    int cv = 4 - __popc(nib);
    int lane = t & 63, wid = t >> 6;
    for (int o = 32; o > 0; o >>= 1) cv += __shfl_down(cv, o);
    if (lane == 0) sv[wid] = cv;
    __syncthreads();
    if (t < 32) mask[(size_t)blockIdx.x * 32 + t] = wds[t];
    if (t == 0) {
        int tot = sv[0] + sv[1] + sv[2] + sv[3];
        atomicAdd(&counts[blockIdx.x >> 3], tot);
        atomicAdd(&nval[blockIdx.x >> 9], tot);
    }
}

// Compaction: val[rank] = (gt, pred) at each valid pos; row prefix computed in-block.
__global__ __launch_bounds__(256) void scatter_kernel(const unsigned int* __restrict__ mask,
                                                      const int* __restrict__ counts,
                                                      const float* __restrict__ gt,
                                                      const float* __restrict__ pred,
                                                      h2* __restrict__ val) {
    int cglob = blockIdx.x;        // 0..1023 (chunk of 8192 px)
    int b  = cglob >> 6;
    int cl = cglob & 63;
    int t = threadIdx.x;
    __shared__ unsigned int svb[256];
    __shared__ int swoff[256];
    __shared__ int wsum[4];
    __shared__ int schunkbase;
    if (t < 64) {                  // wave 0: exclusive prefix of this row's 64 chunk counts
        int v = counts[b * 64 + t];
        int incl = v;
        for (int o = 1; o < 64; o <<= 1) {
            int n = __shfl_up(incl, o);
            if (t >= o) incl += n;
        }
        if (t == cl) schunkbase = incl - v;
    }
    unsigned int vb = ~mask[(size_t)cglob * 256 + t];
    svb[t] = vb;
    int cnt = __popc(vb);
    int lane = t & 63, wid = t >> 6;
    int incl = cnt;
    for (int o = 1; o < 64; o <<= 1) {
        int n = __shfl_up(incl, o);
        if (lane >= o) incl += n;
    }
    if (lane == 63) wsum[wid] = incl;
    __syncthreads();
    int woff = 0;
    for (int i = 0; i < wid; i++) woff += wsum[i];
    swoff[t] = woff + incl - cnt;
    __syncthreads();
    size_t rowb = (size_t)b << 19;
    int chunkbase = schunkbase;
    size_t gbase = rowb + (size_t)cl * 8192;
    int bit = t & 31;
    unsigned int below = (bit == 0) ? 0u : ((1u << bit) - 1u);
    #pragma unroll 4
    for (int i = 0; i < 32; ++i) {
        int e = i * 256 + t;
        unsigned int bits = svb[i * 8 + (t >> 5)];
        if ((bits >> bit) & 1u) {
            int rank = chunkbase + swoff[i * 8 + (t >> 5)] + __popc(bits & below);
            size_t src = gbase + e;
            h2 o; o.x = (_Float16)gt[src]; o.y = (_Float16)pred[src];
            val[rowb + rank] = o;
        }
    }
}

__device__ __forceinline__ float fget(const f4& v, int k) {
    switch (k) { case 0: return v.x; case 1: return v.y; case 2: return v.z; default: return v.w; }
}

// 8 px/thread, 4096 blocks; rows {2x,2x+1} -> XCD x (blockIdx%8 heuristic).
__global__ __launch_bounds__(256) void loss_kernel(const float* __restrict__ pred,
                                                   const float* __restrict__ gt,
                                                   const float* __restrict__ ur,
                                                   const unsigned int* __restrict__ mask,
                                                   const h2* __restrict__ val,
                                                   const int* __restrict__ nv_arr,
                                                   double* __restrict__ acc_ls,
                                                   double* __restrict__ acc_ss,
                                                   unsigned int* __restrict__ cnt_nz,
                                                   unsigned int* __restrict__ cnt_zz) {
    int t = threadIdx.x;
    int bid = blockIdx.x;                       // 4096 blocks
    int b = ((bid & 7) << 1) | ((bid >> 3) & 1);
    int chunk = bid >> 4;                       // 256 chunks per row
    size_t rowb = (size_t)b << 19;
    int n0 = (chunk << 11) + t * 8;
    size_t g0 = rowb + (size_t)n0;
    unsigned int bits =
        (__builtin_nontemporal_load(&mask[g0 >> 5]) >> ((t & 3) << 3)) & 0xFFu;
    int nv = nv_arr[b];
    float fnv = (float)nv;
    f4 U[2], G[2], P[2];
    const f4* up = (const f4*)(ur + g0);
    const f4* gp = (const f4*)(gt + g0);
    const f4* pp = (const f4*)(pred + g0);
    #pragma unroll
    for (int i = 0; i < 2; ++i) {
        U[i] = __builtin_nontemporal_load(up + i);
        G[i] = __builtin_nontemporal_load(gp + i);
        P[i] = __builtin_nontemporal_load(pp + i);
    }
    float ls = 0.f, ss = 0.f;
    int cnz = 0, czz = 0;
    #pragma unroll
    for (int j = 0; j < 8; ++j) {
        if ((bits >> j) & 1u) {                 // invalid pixel
            float urv = fget(U[j >> 2], j & 3);
            int u = min((int)(urv * fnv), nv - 1);
            h2 v = val[rowb + (size_t)u];
            float vx = (float)v.x, vy = (float)v.y;
            float gc = fget(G[j >> 2], j & 3);
            float pc = fget(P[j >> 2], j & 3);
            float d = pc - vy;
            if (gc >= 1.02f * vx)      { ls += __logf(1.f + __expf(-d)); ++cnz; }
            else if (vx > 1.02f * gc)  { ls += __logf(1.f + __expf( d)); ++cnz; }
            else                       { ss += d * d; ++czz; }
        }
    }
    int lane = t & 63, wid = t >> 6;
    __shared__ double sd[4];
    __shared__ unsigned int si[4];
    double lsd = (double)ls, ssd = (double)ss;
    for (int o = 32; o > 0; o >>= 1) lsd += __shfl_down(lsd, o);
    if (lane == 0) sd[wid] = lsd;
    __syncthreads();
    if (t == 0) atomicAdd(&acc_ls[bid & 63], sd[0]+sd[1]+sd[2]+sd[3]);
    __syncthreads();
    for (int o = 32; o > 0; o >>= 1) ssd += __shfl_down(ssd, o);
    if (lane == 0) sd[wid] = ssd;
    __syncthreads();
    if (t == 0) atomicAdd(&acc_ss[bid & 63], sd[0]+sd[1]+sd[2]+sd[3]);
    __syncthreads();
    for (int o = 32; o > 0; o >>= 1) cnz += __shfl_down(cnz, o);
    if (lane == 0) si[wid] = (unsigned int)cnz;
    __syncthreads();
    if (t == 0) atomicAdd(&cnt_nz[bid & 63], si[0]+si[1]+si[2]+si[3]);
    __syncthreads();
    for (int o = 32; o > 0; o >>= 1) czz += __shfl_down(czz, o);
    if (lane == 0) si[wid] = (unsigned int)czz;
    __syncthreads();
    if (t == 0) atomicAdd(&cnt_zz[bid & 63], si[0]+si[1]+si[2]+si[3]);
}

__global__ void finalize_kernel(const double* __restrict__ acc_ls,
                                const double* __restrict__ acc_ss,
                                const unsigned int* __restrict__ cnt_nz,
                                const unsigned int* __restrict__ cnt_zz,
                                float* __restrict__ out) {
    int t = threadIdx.x;   // 64 threads
    double l = acc_ls[t], s2 = acc_ss[t];
    unsigned int a = cnt_nz[t], c = cnt_zz[t];
    for (int o = 32; o > 0; o >>= 1) {
        l  += __shfl_down(l, o);
        s2 += __shfl_down(s2, o);
        a  += __shfl_down(a, o);
        c  += __shfl_down(c, o);
    }
    if (t == 0) out[0] = (float)(l / (double)a + s2 / (double)c);
}

extern "C" void kernel_launch(void* const* d_in, const int* in_sizes, int n_in,
                              void* d_out, int out_size, void* d_ws, size_t ws_size,
                              hipStream_t stream) {
    const float* pred = (const float*)d_in[0];
    const float* gt   = (const float*)d_in[1];
    const float* img  = (const float*)d_in[2];
    const float* ur   = (const float*)d_in[3];
    float* out = (float*)d_out;

    char* ws = (char*)d_ws;
    double*       sum_part = (double*)(ws + 0);
    double*       acc_ls   = (double*)(ws + 512);
    double*       acc_ss   = (double*)(ws + 1024);
    unsigned int* cnt_nz   = (unsigned int*)(ws + 1536);
    unsigned int* cnt_zz   = (unsigned int*)(ws + 1792);
    int*          nval     = (int*)(ws + 2048);
    int*          counts   = (int*)(ws + 4096);
    unsigned int* mask     = (unsigned int*)(ws + 8192);
    h2*           val      = (h2*)(ws + (1 << 21));
    _Float16*     tw       = (_Float16*)(ws + (1 << 21));   // aliases val (pre-scatter)

    (void)hipMemsetAsync(ws, 0, 8192, stream);
    tw_sum_kernel <<<1024, 256, 0, stream>>>(img, sum_part, tw);
    mask_kernel   <<<8192, 256, 0, stream>>>(tw, sum_part, mask, counts, nval);
    scatter_kernel<<<1024, 256, 0, stream>>>(mask, counts, gt, pred, val);
    loss_kernel   <<<4096, 256, 0, stream>>>(pred, gt, ur, mask, val, nval,
                                             acc_ls, acc_ss, cnt_nz, cnt_zz);
    finalize_kernel<<<1, 64, 0, stream>>>(acc_ls, acc_ss, cnt_nz, cnt_zz, out);
}

// Round 12
// 108.507 us; speedup vs baseline: 3.1600x; 1.7797x over previous
//
#include <hip/hip_runtime.h>
#include <hip/hip_bf16.h>
#include <math.h>

#define BB 16
#define CC 3
#define HH 512
#define WW 1024
#define NN (HH * WW)          // 524288 = 2^19
#define BN ((size_t)BB * NN)  // 8388608 = 2^23

typedef __attribute__((ext_vector_type(4))) _Float16 half4;
typedef __attribute__((ext_vector_type(2))) _Float16 h2;
typedef __attribute__((ext_vector_type(4))) float f4;

// ws layout (bytes), first 8 KB zeroed each launch:
//   0    : double sum_part[64]     (0..511)
//   512  : double acc_ls[64]       (512..1023)
//   1024 : double acc_ss[64]       (1024..1535)
//   1536 : uint   cnt_nz[64]       (1536..1791)
//   1792 : uint   cnt_zz[64]       (1792..2047)
//   2048 : int    nval[16]         (2048..2111, written by scatter, plain stores)
//   4096 : int    counts[1024]     (raw per-8192px-chunk valid counts)
//   8192 : uint   mask[BN/32]      invalid bits, 1 MB
//   2MB  : h2     val_list[BN]     (gt_val, pred_val) compacted, 33.5 MB
//          region doubles as tw[BN] (_Float16, 16.8 MB) before scatter.

// 8 rows per block (1024 blocks), register-carried vertical neighbor:
// reads 9 rows, computes 8 -> img traffic 1.125x.
__global__ __launch_bounds__(256) void tw_sum_kernel(const float* __restrict__ img,
                                                     double* __restrict__ sum_part,
                                                     _Float16* __restrict__ tw_out) {
    int t = threadIdx.x;
    int bid = blockIdx.x;                  // 1024 = 16 imgs * 64 row-groups
    int b = bid >> 6;
    int h0 = (bid & 63) * 8;
    const float* base = img + (size_t)b * CC * NN;
    int w0 = t * 4;
    bool haveR = (w0 < WW - 4);
    size_t rb = (size_t)h0 * WW + w0;
    f4 c0 = *(const f4*)(base + rb);
    f4 c1 = *(const f4*)(base + NN + rb);
    f4 c2 = *(const f4*)(base + 2 * NN + rb);
    float e0 = haveR ? base[rb + 4] : 0.f;
    float e1 = haveR ? base[NN + rb + 4] : 0.f;
    float e2 = haveR ? base[2 * NN + rb + 4] : 0.f;
    float rowacc = 0.f;
    #pragma unroll
    for (int r = 0; r < 8; ++r) {
        int h = h0 + r;
        bool haveD = (h < HH - 1);
        size_t db = (size_t)(h + 1) * WW + w0;
        f4 d0, d1, d2;
        float f0, f1, f2;
        if (haveD) {
            d0 = *(const f4*)(base + db);
            d1 = *(const f4*)(base + NN + db);
            d2 = *(const f4*)(base + 2 * NN + db);
            f0 = haveR ? base[db + 4] : 0.f;
            f1 = haveR ? base[NN + db + 4] : 0.f;
            f2 = haveR ? base[2 * NN + db + 4] : 0.f;
        } else {
            d0 = d1 = d2 = (f4)0.f;
            f0 = f1 = f2 = 0.f;
        }
        float a0[5] = {c0.x, c0.y, c0.z, c0.w, e0};
        float a1[5] = {c1.x, c1.y, c1.z, c1.w, e1};
        float a2[5] = {c2.x, c2.y, c2.z, c2.w, e2};
        float b0[4] = {d0.x, d0.y, d0.z, d0.w};
        float b1[4] = {d1.x, d1.y, d1.z, d1.w};
        float b2[4] = {d2.x, d2.y, d2.z, d2.w};
        float tw[4];
        #pragma unroll
        for (int j = 0; j < 4; ++j) {
            float twv = 0.f;
            if (w0 + j < WW - 1)
                twv += (fabsf(a0[j]-a0[j+1]) + fabsf(a1[j]-a1[j+1]) + fabsf(a2[j]-a2[j+1])) / 3.0f;
            if (haveD)
                twv += (fabsf(a0[j]-b0[j]) + fabsf(a1[j]-b1[j]) + fabsf(a2[j]-b2[j])) / 3.0f;
            tw[j] = twv * 0.5f;
        }
        half4 hv; hv.x = (_Float16)tw[0]; hv.y = (_Float16)tw[1];
        hv.z = (_Float16)tw[2]; hv.w = (_Float16)tw[3];
        *(half4*)(tw_out + (size_t)b * NN + (size_t)h * WW + w0) = hv;
        rowacc += (tw[0] + tw[1]) + (tw[2] + tw[3]);
        c0 = d0; c1 = d1; c2 = d2; e0 = f0; e1 = f1; e2 = f2;
    }
    double acc = (double)rowacc;
    int lane = t & 63, wid = t >> 6;
    for (int o = 32; o > 0; o >>= 1) acc += __shfl_down(acc, o);
    __shared__ double sd[4];
    if (lane == 0) sd[wid] = acc;
    __syncthreads();
    if (t == 0) atomicAdd(&sum_part[bid & 63], sd[0]+sd[1]+sd[2]+sd[3]);
}

// 8192 blocks x 256 t x 4 px; writes mask bits + raw chunk counts.
__global__ __launch_bounds__(256) void mask_kernel(const _Float16* __restrict__ tw_in,
                                                   const double* __restrict__ sum_part,
                                                   unsigned int* __restrict__ mask,
                                                   int* __restrict__ counts) {
    __shared__ float s_mean;
    __shared__ unsigned int wds[32];
    __shared__ int sv[4];
    int t = threadIdx.x;
    if (t < 64) {                       // wave-parallel mean: 1 load + shuffle reduce
        double v = sum_part[t];
        for (int o = 32; o > 0; o >>= 1) v += __shfl_down(v, o);
        if (t == 0) s_mean = (float)(v / (double)BN);
    }
    if (t < 32) wds[t] = 0;
    __syncthreads();
    float mean = s_mean;
    size_t g0 = ((size_t)blockIdx.x * 256 + t) * 4;
    half4 hv = *(const half4*)(tw_in + g0);
    unsigned int nib = ((float)hv.x < mean ? 1u : 0u) | ((float)hv.y < mean ? 2u : 0u)
                     | ((float)hv.z < mean ? 4u : 0u) | ((float)hv.w < mean ? 8u : 0u);
    atomicOr(&wds[t >> 3], nib << ((t & 7) * 4));
    int cv = 4 - __popc(nib);
    int lane = t & 63, wid = t >> 6;
    for (int o = 32; o > 0; o >>= 1) cv += __shfl_down(cv, o);
    if (lane == 0) sv[wid] = cv;
    __syncthreads();
    if (t < 32) mask[(size_t)blockIdx.x * 32 + t] = wds[t];
    if (t == 0) atomicAdd(&counts[blockIdx.x >> 3], sv[0]+sv[1]+sv[2]+sv[3]);
}

// Compaction: val[rank] = (gt, pred) at each valid pos; row prefix computed in-block.
// Also writes nval[b] (row total) via plain store from the cl==0 block.
__global__ __launch_bounds__(256) void scatter_kernel(const unsigned int* __restrict__ mask,
                                                      const int* __restrict__ counts,
                                                      const float* __restrict__ gt,
                                                      const float* __restrict__ pred,
                                                      h2* __restrict__ val,
                                                      int* __restrict__ nval) {
    int cglob = blockIdx.x;        // 0..1023 (chunk of 8192 px)
    int b  = cglob >> 6;
    int cl = cglob & 63;
    int t = threadIdx.x;
    __shared__ unsigned int svb[256];
    __shared__ int swoff[256];
    __shared__ int wsum[4];
    __shared__ int schunkbase;
    if (t < 64) {                  // wave 0: exclusive prefix of this row's 64 chunk counts
        int v = counts[b * 64 + t];
        int incl = v;
        for (int o = 1; o < 64; o <<= 1) {
            int n = __shfl_up(incl, o);
            if (t >= o) incl += n;
        }
        if (t == cl) schunkbase = incl - v;
        if (t == 63 && cl == 0) nval[b] = incl;   // row total, plain store
    }
    unsigned int vb = ~mask[(size_t)cglob * 256 + t];
    svb[t] = vb;
    int cnt = __popc(vb);
    int lane = t & 63, wid = t >> 6;
    int incl = cnt;
    for (int o = 1; o < 64; o <<= 1) {
        int n = __shfl_up(incl, o);
        if (lane >= o) incl += n;
    }
    if (lane == 63) wsum[wid] = incl;
    __syncthreads();
    int woff = 0;
    for (int i = 0; i < wid; i++) woff += wsum[i];
    swoff[t] = woff + incl - cnt;
    __syncthreads();
    size_t rowb = (size_t)b << 19;
    int chunkbase = schunkbase;
    size_t gbase = rowb + (size_t)cl * 8192;
    int bit = t & 31;
    unsigned int below = (bit == 0) ? 0u : ((1u << bit) - 1u);
    #pragma unroll 4
    for (int i = 0; i < 32; ++i) {
        int e = i * 256 + t;
        unsigned int bits = svb[i * 8 + (t >> 5)];
        if ((bits >> bit) & 1u) {
            int rank = chunkbase + swoff[i * 8 + (t >> 5)] + __popc(bits & below);
            size_t src = gbase + e;
            h2 o; o.x = (_Float16)gt[src]; o.y = (_Float16)pred[src];
            val[rowb + rank] = o;
        }
    }
}

__device__ __forceinline__ float fget(const f4& v, int k) {
    switch (k) { case 0: return v.x; case 1: return v.y; case 2: return v.z; default: return v.w; }
}

// 8 px/thread, 4096 blocks; rows {2x,2x+1} -> XCD x (blockIdx%8 heuristic).
__global__ __launch_bounds__(256) void loss_kernel(const float* __restrict__ pred,
                                                   const float* __restrict__ gt,
                                                   const float* __restrict__ ur,
                                                   const unsigned int* __restrict__ mask,
                                                   const h2* __restrict__ val,
                                                   const int* __restrict__ nv_arr,
                                                   double* __restrict__ acc_ls,
                                                   double* __restrict__ acc_ss,
                                                   unsigned int* __restrict__ cnt_nz,
                                                   unsigned int* __restrict__ cnt_zz) {
    int t = threadIdx.x;
    int bid = blockIdx.x;                       // 4096 blocks
    int b = ((bid & 7) << 1) | ((bid >> 3) & 1);
    int chunk = bid >> 4;                       // 256 chunks per row
    size_t rowb = (size_t)b << 19;
    int n0 = (chunk << 11) + t * 8;
    size_t g0 = rowb + (size_t)n0;
    unsigned int bits =
        (__builtin_nontemporal_load(&mask[g0 >> 5]) >> ((t & 3) << 3)) & 0xFFu;
    int nv = nv_arr[b];
    float fnv = (float)nv;
    f4 U[2], G[2], P[2];
    const f4* up = (const f4*)(ur + g0);
    const f4* gp = (const f4*)(gt + g0);
    const f4* pp = (const f4*)(pred + g0);
    #pragma unroll
    for (int i = 0; i < 2; ++i) {
        U[i] = __builtin_nontemporal_load(up + i);
        G[i] = __builtin_nontemporal_load(gp + i);
        P[i] = __builtin_nontemporal_load(pp + i);
    }
    float ls = 0.f, ss = 0.f;
    int cnz = 0, czz = 0;
    #pragma unroll
    for (int j = 0; j < 8; ++j) {
        if ((bits >> j) & 1u) {                 // invalid pixel
            float urv = fget(U[j >> 2], j & 3);
            int u = min((int)(urv * fnv), nv - 1);
            h2 v = val[rowb + (size_t)u];
            float vx = (float)v.x, vy = (float)v.y;
            float gc = fget(G[j >> 2], j & 3);
            float pc = fget(P[j >> 2], j & 3);
            float d = pc - vy;
            if (gc >= 1.02f * vx)      { ls += __logf(1.f + __expf(-d)); ++cnz; }
            else if (vx > 1.02f * gc)  { ls += __logf(1.f + __expf( d)); ++cnz; }
            else                       { ss += d * d; ++czz; }
        }
    }
    int lane = t & 63, wid = t >> 6;
    __shared__ double sd[4];
    __shared__ unsigned int si[4];
    double lsd = (double)ls, ssd = (double)ss;
    for (int o = 32; o > 0; o >>= 1) lsd += __shfl_down(lsd, o);
    if (lane == 0) sd[wid] = lsd;
    __syncthreads();
    if (t == 0) atomicAdd(&acc_ls[bid & 63], sd[0]+sd[1]+sd[2]+sd[3]);
    __syncthreads();
    for (int o = 32; o > 0; o >>= 1) ssd += __shfl_down(ssd, o);
    if (lane == 0) sd[wid] = ssd;
    __syncthreads();
    if (t == 0) atomicAdd(&acc_ss[bid & 63], sd[0]+sd[1]+sd[2]+sd[3]);
    __syncthreads();
    for (int o = 32; o > 0; o >>= 1) cnz += __shfl_down(cnz, o);
    if (lane == 0) si[wid] = (unsigned int)cnz;
    __syncthreads();
    if (t == 0) atomicAdd(&cnt_nz[bid & 63], si[0]+si[1]+si[2]+si[3]);
    __syncthreads();
    for (int o = 32; o > 0; o >>= 1) czz += __shfl_down(czz, o);
    if (lane == 0) si[wid] = (unsigned int)czz;
    __syncthreads();
    if (t == 0) atomicAdd(&cnt_zz[bid & 63], si[0]+si[1]+si[2]+si[3]);
}

__global__ void finalize_kernel(const double* __restrict__ acc_ls,
                                const double* __restrict__ acc_ss,
                                const unsigned int* __restrict__ cnt_nz,
                                const unsigned int* __restrict__ cnt_zz,
                                float* __restrict__ out) {
    int t = threadIdx.x;   // 64 threads
    double l = acc_ls[t], s2 = acc_ss[t];
    unsigned int a = cnt_nz[t], c = cnt_zz[t];
    for (int o = 32; o > 0; o >>= 1) {
        l  += __shfl_down(l, o);
        s2 += __shfl_down(s2, o);
        a  += __shfl_down(a, o);
        c  += __shfl_down(c, o);
    }
    if (t == 0) out[0] = (float)(l / (double)a + s2 / (double)c);
}

extern "C" void kernel_launch(void* const* d_in, const int* in_sizes, int n_in,
                              void* d_out, int out_size, void* d_ws, size_t ws_size,
                              hipStream_t stream) {
    const float* pred = (const float*)d_in[0];
    const float* gt   = (const float*)d_in[1];
    const float* img  = (const float*)d_in[2];
    const float* ur   = (const float*)d_in[3];
    float* out = (float*)d_out;

    char* ws = (char*)d_ws;
    double*       sum_part = (double*)(ws + 0);
    double*       acc_ls   = (double*)(ws + 512);
    double*       acc_ss   = (double*)(ws + 1024);
    unsigned int* cnt_nz   = (unsigned int*)(ws + 1536);
    unsigned int* cnt_zz   = (unsigned int*)(ws + 1792);
    int*          nval     = (int*)(ws + 2048);
    int*          counts   = (int*)(ws + 4096);
    unsigned int* mask     = (unsigned int*)(ws + 8192);
    h2*           val      = (h2*)(ws + (1 << 21));
    _Float16*     tw       = (_Float16*)(ws + (1 << 21));   // aliases val (pre-scatter)

    (void)hipMemsetAsync(ws, 0, 8192, stream);
    tw_sum_kernel <<<1024, 256, 0, stream>>>(img, sum_part, tw);
    mask_kernel   <<<8192, 256, 0, stream>>>(tw, sum_part, mask, counts);
    scatter_kernel<<<1024, 256, 0, stream>>>(mask, counts, gt, pred, val, nval);
    loss_kernel   <<<4096, 256, 0, stream>>>(pred, gt, ur, mask, val, nval,
                                             acc_ls, acc_ss, cnt_nz, cnt_zz);
    finalize_kernel<<<1, 64, 0, stream>>>(acc_ls, acc_ss, cnt_nz, cnt_zz, out);
}